// Round 11
// baseline (301.845 us; speedup 1.0000x reference)
//
#include <hip/hip_runtime.h>
#include <math.h>

#define B_   32
#define T_   64
#define D_   300
#define H_   256
#define G4H  1024   // 4*H
#define M_   64
#define C_   5

typedef _Float16 h2v __attribute__((ext_vector_type(2)));
typedef _Float16 h8  __attribute__((ext_vector_type(8)));
typedef float    f4  __attribute__((ext_vector_type(4)));

__device__ __forceinline__ float sigmoidf_(float x) { return 1.0f / (1.0f + expf(-x)); }

__device__ __forceinline__ float dot2_(h2v a, h2v b, float c) {
#if __has_builtin(__builtin_amdgcn_fdot2)
    return __builtin_amdgcn_fdot2(a, b, c, false);
#else
    return c + (float)a[0] * (float)b[0] + (float)a[1] * (float)b[1];
#endif
}

// ---------------------------------------------------------------------------
// K1: length[b]. Coalesced: 16 lanes per t read 64B-contiguous segments.
// ---------------------------------------------------------------------------
__global__ void __launch_bounds__(1024)
k_length(const float* __restrict__ x, int* __restrict__ length) {
    const int b   = blockIdx.x;
    const int tid = threadIdx.x;
    const int t   = tid >> 4;        // 0..63
    const int j   = tid & 15;        // lane within 16-group

    __shared__ int cnt;
    if (tid == 0) cnt = 0;
    __syncthreads();

    const float* row = x + (size_t)(b * T_ + t) * D_;
    float mv = 0.f;
    #pragma unroll
    for (int i = 0; i < 19; ++i) {
        int d = j + 16 * i;
        if (d < D_) mv = fmaxf(mv, fabsf(row[d]));
    }
    #pragma unroll
    for (int off = 8; off >= 1; off >>= 1) mv = fmaxf(mv, __shfl_xor(mv, off));
    if (j == 0 && mv > 0.f) atomicAdd(&cnt, 1);
    __syncthreads();
    if (tid == 0) length[b] = cnt;
}

// ---------------------------------------------------------------------------
// K2: xw = x-part of gate pre-activations (+ bias). f16 MFMA GEMM.
// ---------------------------------------------------------------------------
__global__ void __launch_bounds__(256)
k_xw(const float* __restrict__ x,
     const float* __restrict__ Wfw, const float* __restrict__ bfw,
     const float* __restrict__ Wbw, const float* __restrict__ bbw,
     float* __restrict__ xw) {
    const int nt  = blockIdx.x;       // 0..15 col tile
    const int mt  = blockIdx.y;       // 0..15 row tile
    const int tid = threadIdx.x;      // 256
    const int w   = tid >> 6;         // wave 0..3
    const int l   = tid & 63;
    const int n0  = nt * 128, m0 = mt * 128;
    const int dir = n0 >> 10;               // 1024%128==0: tiles don't straddle
    const float* W    = dir ? Wbw : Wfw;
    const float* bias = dir ? bbw : bfw;
    const int ncol0 = n0 & 1023;

    __shared__ __align__(16) _Float16 As[128][40];  // 32 k + 8 pad
    __shared__ __align__(16) _Float16 Bs[128][40];  // [col][k]

    f4 acc[4][4];
    #pragma unroll
    for (int i = 0; i < 4; ++i)
        #pragma unroll
        for (int j = 0; j < 4; ++j) acc[i][j] = (f4){0.f, 0.f, 0.f, 0.f};

    const int wr = (w >> 1) * 64;   // wave row quadrant
    const int wc = (w & 1) * 64;    // wave col quadrant

    for (int k0 = 0; k0 < 320; k0 += 32) {
        // A: 128 rows x 32 k, float4 along k (D_=300 is 4-aligned)
        #pragma unroll
        for (int p = 0; p < 4; ++p) {
            int row = (tid >> 3) + p * 32;
            int kq  = tid & 7;
            int k   = k0 + kq * 4;
            f4 v = (k < D_) ? *(const f4*)&x[(size_t)(m0 + row) * D_ + k]
                            : (f4){0.f, 0.f, 0.f, 0.f};
            _Float16* dst = &As[row][kq * 4];
            dst[0] = (_Float16)v[0]; dst[1] = (_Float16)v[1];
            dst[2] = (_Float16)v[2]; dst[3] = (_Float16)v[3];
        }
        // B: 32 k x 128 cols, float4 along col
        #pragma unroll
        for (int p = 0; p < 4; ++p) {
            int kk   = (tid >> 5) + p * 8;
            int colq = tid & 31;
            int k    = k0 + kk;
            f4 v = (k < D_) ? *(const f4*)&W[(size_t)k * G4H + ncol0 + colq * 4]
                            : (f4){0.f, 0.f, 0.f, 0.f};
            #pragma unroll
            for (int i = 0; i < 4; ++i) Bs[colq * 4 + i][kk] = (_Float16)v[i];
        }
        __syncthreads();

        h8 afr[4], bfr[4];
        #pragma unroll
        for (int fr = 0; fr < 4; ++fr)
            afr[fr] = *(const h8*)&As[wr + fr * 16 + (l & 15)][(l >> 4) * 8];
        #pragma unroll
        for (int fc = 0; fc < 4; ++fc)
            bfr[fc] = *(const h8*)&Bs[wc + fc * 16 + (l & 15)][(l >> 4) * 8];
        #pragma unroll
        for (int fr = 0; fr < 4; ++fr)
            #pragma unroll
            for (int fc = 0; fc < 4; ++fc)
                acc[fr][fc] = __builtin_amdgcn_mfma_f32_16x16x32_f16(
                    afr[fr], bfr[fc], acc[fr][fc], 0, 0, 0);
        __syncthreads();
    }

    #pragma unroll
    for (int fc = 0; fc < 4; ++fc) {
        int col = ncol0 + wc + fc * 16 + (l & 15);
        float bv = bias[col];
        #pragma unroll
        for (int fr = 0; fr < 4; ++fr) {
            #pragma unroll
            for (int e = 0; e < 4; ++e) {
                int row = m0 + wr + fr * 16 + (l >> 4) * 4 + e;
                xw[(size_t)dir * 2048 * G4H + (size_t)row * G4H + col] =
                    acc[fr][fc][e] + bv;
            }
        }
    }
}

// ---------------------------------------------------------------------------
// K3 phases (round-8 proven protocol, factored for 2-chain interleave)
// ---------------------------------------------------------------------------
__device__ __forceinline__ void dot_phase(const _Float16* HL, float* ZF,
                                          const h2v* wreg, float xv,
                                          int khalf, int c, int l) {
    float acc = 0.f;
    const uint2* hp = (const uint2*)(HL + khalf * 128);
    #pragma unroll
    for (int j = 0; j < 32; ++j) {
        uint2 hv = hp[j];
        acc = dot2_(wreg[2 * j],     __builtin_bit_cast(h2v, hv.x), acc);
        acc = dot2_(wreg[2 * j + 1], __builtin_bit_cast(h2v, hv.y), acc);
    }
    acc += __shfl_xor(acc, 32);
    if (l < 32) ZF[c] = acc + xv;
}

__device__ __forceinline__ void gates_phase(const float* ZF, float* HO, _Float16* HL,
                                            unsigned* exslot, float& cst, float& hprev,
                                            int len, int tt, unsigned tag,
                                            int tid, int js) {
    if (tid < 64) {
        float zi = ZF[tid], zj = ZF[64 + tid], zf = ZF[128 + tid], zo = ZF[192 + tid];
        float cn = sigmoidf_(zf + 1.0f) * cst + sigmoidf_(zi) * tanhf(zj);
        float hn = sigmoidf_(zo) * tanhf(cn);
        bool  msk = (tt < len);
        float ho  = msk ? hn : 0.f;
        float hk2 = msk ? hn : hprev;
        if (msk) cst = cn;
        hprev = hk2;
        HO[tid] = ho;
        HL[js * 64 + tid] = (_Float16)hk2;   // own slice straight into LDS
        unsigned bits = (__float_as_uint(hk2) & ~1u) | tag;
        __hip_atomic_store(&exslot[js * 64 + tid], bits,
                           __ATOMIC_RELAXED, __HIP_MEMORY_SCOPE_AGENT);
    }
}

__device__ __forceinline__ void poll_phase(_Float16* HL, unsigned* exslot,
                                           unsigned tag, int tid, int js) {
    if (tid < 256 && (tid >> 6) != js) {
        unsigned v; unsigned it = 0;
        for (;;) {
            v = __hip_atomic_load(&exslot[tid],
                                  __ATOMIC_RELAXED, __HIP_MEMORY_SCOPE_AGENT);
            if ((v & 1u) == tag) break;
            __builtin_amdgcn_s_sleep(1);
            if (++it > (1u << 20)) break;   // safety valve: wrong > wedged
        }
        HL[tid] = (_Float16)__uint_as_float(v);
    }
}

// ---------------------------------------------------------------------------
// K3: LSTM recurrence + FUSED einsum, TWO chains per block (latency-
// multiplexed). 128 blocks = 32 pair-groups (dir, b0=pg&15, b1=b0+16) x 4
// column-slices. Both chains share dir -> one wreg set serves both.
// Per iteration: dot_A | gates_A+publish_A | dot_B | gates_B+publish_B |
// MAC_A | poll_A | MAC_B | poll_B  — chain B's compute and the einsum MACs
// hide chain A's L3 publish->poll round trip (~2.2 us), retiring 2 chain-
// steps per RTT. Protocol = round-8 proven tagged-data (fp32 LSB parity,
// 4-slot ring, relaxed agent atomics), byte-identical per chain.
// ---------------------------------------------------------------------------
__global__ void __launch_bounds__(512, 2)
k_lstm(const float* __restrict__ Wfw, const float* __restrict__ Wbw,
       const float* __restrict__ xw, const int* __restrict__ length,
       const float* __restrict__ ent, float* __restrict__ partials,
       unsigned* __restrict__ exbuf) {
    const int bid = blockIdx.x;      // 0..127
    const int js  = bid >> 5;        // 0..3 column slice
    const int pg  = bid & 31;        // pair group; bid%8 == pg%8 -> same XCD per group
    const int dir = pg >> 4;
    const int b0  = pg & 15;
    const int b1  = b0 + 16;
    const int gA  = dir * 32 + b0;   // chain ids (exbuf regions, as round 8)
    const int gB  = dir * 32 + b1;
    const int tid = threadIdx.x;     // 0..511
    const int w   = tid >> 6;        // wave 0..7
    const int l   = tid & 63;
    const int c     = w * 32 + (l & 31);   // gate-col 0..255 (gate = c>>6, jj = c&63)
    const int khalf = l >> 5;              // 0: k 0..127, 1: k 128..255
    const int colg  = (c >> 6) * 256 + js * 64 + (c & 63);
    const int m8  = tid >> 3;        // einsum m 0..63
    const int oct = tid & 7;         // einsum d-octet

    __shared__ __align__(8) _Float16 hl_A[256];
    __shared__ __align__(8) _Float16 hl_B[256];
    __shared__ float zfin_A[256];
    __shared__ float zfin_B[256];
    __shared__ float ho_A[64];
    __shared__ float ho_B[64];

    const float* Wg = dir ? Wbw : Wfw;

    // ---- stage W_h column-half into registers (shared by both chains) ----
    h2v wreg[64];
    #pragma unroll
    for (int p = 0; p < 64; ++p) {
        int k = khalf * 128 + 2 * p;
        float w0 = Wg[(size_t)(D_ + k) * G4H + colg];
        float w1 = Wg[(size_t)(D_ + k + 1) * G4H + colg];
        h2v t; t[0] = (_Float16)w0; t[1] = (_Float16)w1;
        wreg[p] = t;
    }

    if (tid < 256) { hl_A[tid] = (_Float16)0.f; hl_B[tid] = (_Float16)0.f; }
    const int lenA = length[b0];
    const int lenB = length[b1];
    const size_t xrowA = (size_t)(dir * B_ + b0) * T_;
    const size_t xrowB = (size_t)(dir * B_ + b1) * T_;
    const float* entpA = ent + (((size_t)m8 * B_ + b0) * T_) * 512
                             + dir * 256 + js * 64 + oct * 8;
    const float* entpB = ent + (((size_t)m8 * B_ + b1) * T_) * 512
                             + dir * 256 + js * 64 + oct * 8;
    f4 aA0 = (f4){0.f, 0.f, 0.f, 0.f}, aA1 = (f4){0.f, 0.f, 0.f, 0.f};
    f4 aB0 = (f4){0.f, 0.f, 0.f, 0.f}, aB1 = (f4){0.f, 0.f, 0.f, 0.f};
    __syncthreads();

    float cstA = 0.f, hprevA = 0.f;
    float cstB = 0.f, hprevB = 0.f;

    for (int s = 0; s < T_; ++s) {
        const int tt = dir ? (T_ - 1 - s) : s;
        const unsigned tag = ((unsigned)(s >> 2) & 1u) ^ 1u;   // ring-cycle parity
        unsigned* slotA = exbuf + ((size_t)gA * 4 + (s & 3)) * 256;
        unsigned* slotB = exbuf + ((size_t)gB * 4 + (s & 3)) * 256;

        // prefetch streams for this step (independent of recurrence)
        f4 eA0 = *(const f4*)(entpA + (size_t)tt * 512);
        f4 eA1 = *(const f4*)(entpA + (size_t)tt * 512 + 4);
        f4 eB0 = *(const f4*)(entpB + (size_t)tt * 512);
        f4 eB1 = *(const f4*)(entpB + (size_t)tt * 512 + 4);
        float xvA = 0.f, xvB = 0.f;
        if (l < 32) {
            xvA = xw[(xrowA + tt) * G4H + colg];
            xvB = xw[(xrowB + tt) * G4H + colg];
        }

        dot_phase(hl_A, zfin_A, wreg, xvA, khalf, c, l);
        __syncthreads();                                   // (1) zfin_A ready

        gates_phase(zfin_A, ho_A, hl_A, slotA, cstA, hprevA, lenA, tt, tag, tid, js);
        dot_phase(hl_B, zfin_B, wreg, xvB, khalf, c, l);
        __syncthreads();                                   // (2) zfin_B + ho_A ready

        gates_phase(zfin_B, ho_B, hl_B, slotB, cstB, hprevB, lenB, tt, tag, tid, js);
        #pragma unroll
        for (int i = 0; i < 4; ++i) {                      // MAC_A (hides A's RTT)
            aA0[i] += eA0[i] * ho_A[oct * 8 + i];
            aA1[i] += eA1[i] * ho_A[oct * 8 + 4 + i];
        }
        poll_phase(hl_A, slotA, tag, tid, js);
        __syncthreads();                                   // (3) hl_A complete + ho_B ready

        #pragma unroll
        for (int i = 0; i < 4; ++i) {                      // MAC_B (hides B's RTT)
            aB0[i] += eB0[i] * ho_B[oct * 8 + i];
            aB1[i] += eB1[i] * ho_B[oct * 8 + 4 + i];
        }
        poll_phase(hl_B, slotB, tag, tid, js);
        __syncthreads();                                   // (4) hl_B complete
    }

    // ---- write partials: unique regions per block: (m8, b, 64-d slice) ----
    float* pA = partials + ((size_t)m8 * B_ + b0) * 512 + dir * 256 + js * 64 + oct * 8;
    *(f4*)pA = aA0;
    *(f4*)(pA + 4) = aA1;
    float* pB = partials + ((size_t)m8 * B_ + b1) * 512 + dir * 256 + js * 64 + oct * 8;
    *(f4*)pB = aB0;
    *(f4*)(pB + 4) = aB1;
}

// ---------------------------------------------------------------------------
// K5: reduce partials over b -> output_f, then l1 = relu(of @ W1 + b1)
// ---------------------------------------------------------------------------
__global__ void k_l1(const float* __restrict__ partials, const float* __restrict__ W1,
                     const float* __restrict__ b1, float* __restrict__ l1) {
    const int m = blockIdx.x;
    const int j = threadIdx.x;  // 0..255
    __shared__ float of[512];
    for (int d = j; d < 512; d += 256) {
        float s = 0.f;
        #pragma unroll
        for (int cc = 0; cc < 32; ++cc) s += partials[((size_t)m * B_ + cc) * 512 + d];
        of[d] = s * (1.0f / T_);
    }
    __syncthreads();
    float z = b1[j];
    for (int k = 0; k < 512; ++k) z += of[k] * W1[(size_t)k * H_ + j];
    l1[(size_t)m * H_ + j] = fmaxf(z, 0.f);
}

// ---------------------------------------------------------------------------
// K6: head + loss
// ---------------------------------------------------------------------------
__global__ void k_head(const float* __restrict__ l1, const float* __restrict__ W2,
                       const float* __restrict__ b2, const int* __restrict__ labels,
                       float* __restrict__ out) {
    const int tid = threadIdx.x;  // 320 threads
    __shared__ float red[320];
    float term = 0.f;
    if (tid < 320) {
        int m = tid / 5, cc = tid % 5;
        float z = b2[cc];
        for (int k = 0; k < H_; ++k) z += l1[(size_t)m * H_ + k] * W2[(size_t)k * C_ + cc];
        float p = 1.f / (1.f + expf(-z));
        out[tid] = p;
        term = -(float)labels[tid] * logf(p);
    }
    red[tid] = term;
    __syncthreads();
    if (tid == 0) {
        float s = 0.f;
        for (int i = 0; i < 320; ++i) s += red[i];
        out[320] = s / (float)C_;
    }
}

// ---------------------------------------------------------------------------
extern "C" void kernel_launch(void* const* d_in, const int* in_sizes, int n_in,
                              void* d_out, int out_size, void* d_ws, size_t ws_size,
                              hipStream_t stream) {
    const float* x      = (const float*)d_in[0];
    const float* ent    = (const float*)d_in[1];
    const int*   labels = (const int*)d_in[2];
    const float* Wfw    = (const float*)d_in[3];
    const float* bfw    = (const float*)d_in[4];
    const float* Wbw    = (const float*)d_in[5];
    const float* bbw    = (const float*)d_in[6];
    const float* W1     = (const float*)d_in[7];
    const float* b1     = (const float*)d_in[8];
    const float* W2     = (const float*)d_in[9];
    const float* b2     = (const float*)d_in[10];
    float* out = (float*)d_out;

    float*    ws       = (float*)d_ws;
    float*    xw       = ws;                            // 4,194,304 floats
    unsigned* exbuf    = (unsigned*)(xw + 4194304);     // 65,536 u32 (64 chains * 4 * 256)
    float*    l1       = (float*)(exbuf + 65536);       // 16,384 floats
    int*      length   = (int*)(l1 + 16384);            // 32 ints
    float*    partials = (float*)(length + 32);         // 1,048,576 floats

    k_length<<<32, 1024, 0, stream>>>(x, length);
    k_xw<<<dim3(16, 16), 256, 0, stream>>>(x, Wfw, bfw, Wbw, bbw, xw);
    k_lstm<<<128, 512, 0, stream>>>(Wfw, Wbw, xw, length, ent, partials, exbuf);
    k_l1<<<64, 256, 0, stream>>>(partials, W1, b1, l1);
    k_head<<<1, 320, 0, stream>>>(l1, W2, b2, labels, out);
}

// Round 12
// 207.907 us; speedup vs baseline: 1.4518x; 1.4518x over previous
//
#include <hip/hip_runtime.h>
#include <math.h>

#define B_   32
#define T_   64
#define D_   300
#define H_   256
#define G4H  1024   // 4*H
#define M_   64
#define C_   5

typedef _Float16 h2v __attribute__((ext_vector_type(2)));
typedef _Float16 h8  __attribute__((ext_vector_type(8)));
typedef float    f4  __attribute__((ext_vector_type(4)));

__device__ __forceinline__ float sigmoidf_(float x) { return 1.0f / (1.0f + expf(-x)); }

__device__ __forceinline__ float dot2_(h2v a, h2v b, float c) {
#if __has_builtin(__builtin_amdgcn_fdot2)
    return __builtin_amdgcn_fdot2(a, b, c, false);
#else
    return c + (float)a[0] * (float)b[0] + (float)a[1] * (float)b[1];
#endif
}

// ---------------------------------------------------------------------------
// K1: length[b]. Coalesced: 16 lanes per t read 64B-contiguous segments.
// ---------------------------------------------------------------------------
__global__ void __launch_bounds__(1024)
k_length(const float* __restrict__ x, int* __restrict__ length) {
    const int b   = blockIdx.x;
    const int tid = threadIdx.x;
    const int t   = tid >> 4;        // 0..63
    const int j   = tid & 15;        // lane within 16-group

    __shared__ int cnt;
    if (tid == 0) cnt = 0;
    __syncthreads();

    const float* row = x + (size_t)(b * T_ + t) * D_;
    float mv = 0.f;
    #pragma unroll
    for (int i = 0; i < 19; ++i) {
        int d = j + 16 * i;
        if (d < D_) mv = fmaxf(mv, fabsf(row[d]));
    }
    #pragma unroll
    for (int off = 8; off >= 1; off >>= 1) mv = fmaxf(mv, __shfl_xor(mv, off));
    if (j == 0 && mv > 0.f) atomicAdd(&cnt, 1);
    __syncthreads();
    if (tid == 0) length[b] = cnt;
}

// ---------------------------------------------------------------------------
// K2: xw = x-part of gate pre-activations (+ bias). f16 MFMA GEMM.
// ---------------------------------------------------------------------------
__global__ void __launch_bounds__(256)
k_xw(const float* __restrict__ x,
     const float* __restrict__ Wfw, const float* __restrict__ bfw,
     const float* __restrict__ Wbw, const float* __restrict__ bbw,
     float* __restrict__ xw) {
    const int nt  = blockIdx.x;       // 0..15 col tile
    const int mt  = blockIdx.y;       // 0..15 row tile
    const int tid = threadIdx.x;      // 256
    const int w   = tid >> 6;         // wave 0..3
    const int l   = tid & 63;
    const int n0  = nt * 128, m0 = mt * 128;
    const int dir = n0 >> 10;               // 1024%128==0: tiles don't straddle
    const float* W    = dir ? Wbw : Wfw;
    const float* bias = dir ? bbw : bfw;
    const int ncol0 = n0 & 1023;

    __shared__ __align__(16) _Float16 As[128][40];  // 32 k + 8 pad
    __shared__ __align__(16) _Float16 Bs[128][40];  // [col][k]

    f4 acc[4][4];
    #pragma unroll
    for (int i = 0; i < 4; ++i)
        #pragma unroll
        for (int j = 0; j < 4; ++j) acc[i][j] = (f4){0.f, 0.f, 0.f, 0.f};

    const int wr = (w >> 1) * 64;   // wave row quadrant
    const int wc = (w & 1) * 64;    // wave col quadrant

    for (int k0 = 0; k0 < 320; k0 += 32) {
        // A: 128 rows x 32 k, float4 along k (D_=300 is 4-aligned)
        #pragma unroll
        for (int p = 0; p < 4; ++p) {
            int row = (tid >> 3) + p * 32;
            int kq  = tid & 7;
            int k   = k0 + kq * 4;
            f4 v = (k < D_) ? *(const f4*)&x[(size_t)(m0 + row) * D_ + k]
                            : (f4){0.f, 0.f, 0.f, 0.f};
            _Float16* dst = &As[row][kq * 4];
            dst[0] = (_Float16)v[0]; dst[1] = (_Float16)v[1];
            dst[2] = (_Float16)v[2]; dst[3] = (_Float16)v[3];
        }
        // B: 32 k x 128 cols, float4 along col
        #pragma unroll
        for (int p = 0; p < 4; ++p) {
            int kk   = (tid >> 5) + p * 8;
            int colq = tid & 31;
            int k    = k0 + kk;
            f4 v = (k < D_) ? *(const f4*)&W[(size_t)k * G4H + ncol0 + colq * 4]
                            : (f4){0.f, 0.f, 0.f, 0.f};
            #pragma unroll
            for (int i = 0; i < 4; ++i) Bs[colq * 4 + i][kk] = (_Float16)v[i];
        }
        __syncthreads();

        h8 afr[4], bfr[4];
        #pragma unroll
        for (int fr = 0; fr < 4; ++fr)
            afr[fr] = *(const h8*)&As[wr + fr * 16 + (l & 15)][(l >> 4) * 8];
        #pragma unroll
        for (int fc = 0; fc < 4; ++fc)
            bfr[fc] = *(const h8*)&Bs[wc + fc * 16 + (l & 15)][(l >> 4) * 8];
        #pragma unroll
        for (int fr = 0; fr < 4; ++fr)
            #pragma unroll
            for (int fc = 0; fc < 4; ++fc)
                acc[fr][fc] = __builtin_amdgcn_mfma_f32_16x16x32_f16(
                    afr[fr], bfr[fc], acc[fr][fc], 0, 0, 0);
        __syncthreads();
    }

    #pragma unroll
    for (int fc = 0; fc < 4; ++fc) {
        int col = ncol0 + wc + fc * 16 + (l & 15);
        float bv = bias[col];
        #pragma unroll
        for (int fr = 0; fr < 4; ++fr) {
            #pragma unroll
            for (int e = 0; e < 4; ++e) {
                int row = m0 + wr + fr * 16 + (l >> 4) * 4 + e;
                xw[(size_t)dir * 2048 * G4H + (size_t)row * G4H + col] =
                    acc[fr][fc][e] + bv;
            }
        }
    }
}

// ---------------------------------------------------------------------------
// K3: LSTM recurrence + FUSED einsum (round-8 proven structure) with
// DOUBLE-BUFFERED stream prefetch: step s+1's ent/xw loads issue at the
// top of iteration s (load-to-use ~2 iterations, 64 B/thread in flight) —
// the next step's burst overlaps this step's poll-spin idle window.
// Exchange protocol unchanged: tagged-data, fp32 LSB = ring-cycle parity,
// relaxed agent atomics, 4-slot ring, 256 blocks = 64 groups x 4 slices.
// ---------------------------------------------------------------------------
__global__ void __launch_bounds__(512)
k_lstm(const float* __restrict__ Wfw, const float* __restrict__ Wbw,
       const float* __restrict__ xw, const int* __restrict__ length,
       const float* __restrict__ ent, float* __restrict__ partials,
       unsigned* __restrict__ exbuf) {
    const int bid = blockIdx.x;
    const int js  = bid >> 6;        // 0..3 column slice
    const int g   = bid & 63;        // group id
    const int dir = g >> 5;
    const int b   = g & 31;
    const int tid = threadIdx.x;     // 0..511
    const int w   = tid >> 6;        // wave 0..7
    const int l   = tid & 63;
    const int c     = w * 32 + (l & 31);   // gate-col 0..255 (gate = c>>6, jj = c&63)
    const int khalf = l >> 5;              // 0: k 0..127, 1: k 128..255
    const int colg  = (c >> 6) * 256 + js * 64 + (c & 63);
    const int m8  = tid >> 3;        // einsum m 0..63
    const int oct = tid & 7;         // einsum d-octet

    __shared__ __align__(8) _Float16 hl_h[256];
    __shared__ float zfin[256];
    __shared__ float ho_l[64];

    const float* Wg = dir ? Wbw : Wfw;

    // ---- stage this thread's W_h column-half into registers (f16 pairs) ----
    h2v wreg[64];
    #pragma unroll
    for (int p = 0; p < 64; ++p) {
        int k = khalf * 128 + 2 * p;
        float w0 = Wg[(size_t)(D_ + k) * G4H + colg];
        float w1 = Wg[(size_t)(D_ + k + 1) * G4H + colg];
        h2v t; t[0] = (_Float16)w0; t[1] = (_Float16)w1;
        wreg[p] = t;
    }

    if (tid < 256) hl_h[tid] = (_Float16)0.f;
    const int len = length[b];
    const size_t xrow = (size_t)(dir * B_ + b) * T_;
    // einsum base: ent[m8, b, t, dir*256 + js*64 + oct*8]
    const float* entp = ent + (((size_t)m8 * B_ + b) * T_) * 512
                            + dir * 256 + js * 64 + oct * 8;
    f4 accA = (f4){0.f, 0.f, 0.f, 0.f};
    f4 accB = (f4){0.f, 0.f, 0.f, 0.f};

    // ---- prefetch step-0 stream operands ----
    const int tt0 = dir ? (T_ - 1) : 0;
    f4 e0 = *(const f4*)(entp + (size_t)tt0 * 512);
    f4 e1 = *(const f4*)(entp + (size_t)tt0 * 512 + 4);
    float xv = (l < 32) ? xw[(xrow + tt0) * G4H + colg] : 0.f;
    __syncthreads();

    float cst = 0.f, hprev = 0.f;

    for (int s = 0; s < T_; ++s) {
        const int tt = dir ? (T_ - 1 - s) : s;
        const unsigned tag = ((unsigned)(s >> 2) & 1u) ^ 1u;   // ring-cycle parity
        const size_t slotBase = ((size_t)g * 4 + (s & 3)) * 256;

        // ---- issue step s+1's stream loads NOW (used at end of s+1) ----
        const int sn  = (s + 1 < T_) ? s + 1 : s;          // clamp: harmless re-read
        const int ttn = dir ? (T_ - 1 - sn) : sn;
        f4 e0n = *(const f4*)(entp + (size_t)ttn * 512);
        f4 e1n = *(const f4*)(entp + (size_t)ttn * 512 + 4);
        float xvn = (l < 32) ? xw[(xrow + ttn) * G4H + colg] : 0.f;

        // ---- dot: this col, this k-half: 32 broadcast b64 reads + 64 fdot2 ----
        float acc = 0.f;
        const uint2* hp = (const uint2*)&hl_h[khalf * 128];
        #pragma unroll
        for (int j = 0; j < 32; ++j) {
            uint2 hv = hp[j];
            acc = dot2_(wreg[2 * j],     __builtin_bit_cast(h2v, hv.x), acc);
            acc = dot2_(wreg[2 * j + 1], __builtin_bit_cast(h2v, hv.y), acc);
        }
        acc += __shfl_xor(acc, 32);          // combine the two k-halves
        if (l < 32) zfin[c] = acc + xv;
        __syncthreads();

        // ---- gates for this block's 64 h-columns; publish tagged h slice ----
        if (tid < 64) {
            float zi = zfin[tid], zj = zfin[64 + tid], zf = zfin[128 + tid], zo = zfin[192 + tid];
            float cn = sigmoidf_(zf + 1.0f) * cst + sigmoidf_(zi) * tanhf(zj);
            float hn = sigmoidf_(zo) * tanhf(cn);
            bool  msk = (tt < len);
            float ho  = msk ? hn : 0.f;
            float hk2 = msk ? hn : hprev;
            if (msk) cst = cn;
            hprev = hk2;
            int jglob = js * 64 + tid;
            ho_l[tid] = ho;                  // masked output for fused einsum
            hl_h[jglob] = (_Float16)hk2;     // own slice straight into LDS
            unsigned bits = (__float_as_uint(hk2) & ~1u) | tag;
            __hip_atomic_store(&exbuf[slotBase + jglob], bits,
                               __ATOMIC_RELAXED, __HIP_MEMORY_SCOPE_AGENT);
        }

        // ---- poll peers' tagged words (single L3 trip, relaxed) ----
        if (tid < 256 && (tid >> 6) != js) {
            unsigned v; unsigned it = 0;
            for (;;) {
                v = __hip_atomic_load(&exbuf[slotBase + tid],
                                      __ATOMIC_RELAXED, __HIP_MEMORY_SCOPE_AGENT);
                if ((v & 1u) == tag) break;
                __builtin_amdgcn_s_sleep(1);
                if (++it > (1u << 20)) break;   // safety valve: wrong > wedged
            }
            hl_h[tid] = (_Float16)__uint_as_float(v);
        }
        __syncthreads();

        // ---- fused einsum MAC (consumes step-s operands prefetched last iter) ----
        #pragma unroll
        for (int i = 0; i < 4; ++i) {
            accA[i] += e0[i] * ho_l[oct * 8 + i];
            accB[i] += e1[i] * ho_l[oct * 8 + 4 + i];
        }
        e0 = e0n; e1 = e1n; xv = xvn;        // rotate double buffer
    }

    // ---- write partials: unique region per block: (m8, b, 64-d slice) ----
    float* pp = partials + ((size_t)m8 * B_ + b) * 512 + dir * 256 + js * 64 + oct * 8;
    *(f4*)pp = accA;
    *(f4*)(pp + 4) = accB;
}

// ---------------------------------------------------------------------------
// K5: reduce partials over b -> output_f, then l1 = relu(of @ W1 + b1)
// ---------------------------------------------------------------------------
__global__ void k_l1(const float* __restrict__ partials, const float* __restrict__ W1,
                     const float* __restrict__ b1, float* __restrict__ l1) {
    const int m = blockIdx.x;
    const int j = threadIdx.x;  // 0..255
    __shared__ float of[512];
    for (int d = j; d < 512; d += 256) {
        float s = 0.f;
        #pragma unroll
        for (int cc = 0; cc < 32; ++cc) s += partials[((size_t)m * B_ + cc) * 512 + d];
        of[d] = s * (1.0f / T_);
    }
    __syncthreads();
    float z = b1[j];
    for (int k = 0; k < 512; ++k) z += of[k] * W1[(size_t)k * H_ + j];
    l1[(size_t)m * H_ + j] = fmaxf(z, 0.f);
}

// ---------------------------------------------------------------------------
// K6: head + loss
// ---------------------------------------------------------------------------
__global__ void k_head(const float* __restrict__ l1, const float* __restrict__ W2,
                       const float* __restrict__ b2, const int* __restrict__ labels,
                       float* __restrict__ out) {
    const int tid = threadIdx.x;  // 320 threads
    __shared__ float red[320];
    float term = 0.f;
    if (tid < 320) {
        int m = tid / 5, cc = tid % 5;
        float z = b2[cc];
        for (int k = 0; k < H_; ++k) z += l1[(size_t)m * H_ + k] * W2[(size_t)k * C_ + cc];
        float p = 1.f / (1.f + expf(-z));
        out[tid] = p;
        term = -(float)labels[tid] * logf(p);
    }
    red[tid] = term;
    __syncthreads();
    if (tid == 0) {
        float s = 0.f;
        for (int i = 0; i < 320; ++i) s += red[i];
        out[320] = s / (float)C_;
    }
}

// ---------------------------------------------------------------------------
extern "C" void kernel_launch(void* const* d_in, const int* in_sizes, int n_in,
                              void* d_out, int out_size, void* d_ws, size_t ws_size,
                              hipStream_t stream) {
    const float* x      = (const float*)d_in[0];
    const float* ent    = (const float*)d_in[1];
    const int*   labels = (const int*)d_in[2];
    const float* Wfw    = (const float*)d_in[3];
    const float* bfw    = (const float*)d_in[4];
    const float* Wbw    = (const float*)d_in[5];
    const float* bbw    = (const float*)d_in[6];
    const float* W1     = (const float*)d_in[7];
    const float* b1     = (const float*)d_in[8];
    const float* W2     = (const float*)d_in[9];
    const float* b2     = (const float*)d_in[10];
    float* out = (float*)d_out;

    float*    ws       = (float*)d_ws;
    float*    xw       = ws;                            // 4,194,304 floats
    unsigned* exbuf    = (unsigned*)(xw + 4194304);     // 65,536 u32
    float*    l1       = (float*)(exbuf + 65536);       // 16,384 floats
    int*      length   = (int*)(l1 + 16384);            // 32 ints
    float*    partials = (float*)(length + 32);         // 1,048,576 floats

    k_length<<<32, 1024, 0, stream>>>(x, length);
    k_xw<<<dim3(16, 16), 256, 0, stream>>>(x, Wfw, bfw, Wbw, bbw, xw);
    k_lstm<<<256, 512, 0, stream>>>(Wfw, Wbw, xw, length, ent, partials, exbuf);
    k_l1<<<64, 256, 0, stream>>>(partials, W1, b1, l1);
    k_head<<<1, 320, 0, stream>>>(l1, W2, b2, labels, out);
}

// Round 13
// 205.060 us; speedup vs baseline: 1.4720x; 1.0139x over previous
//
#include <hip/hip_runtime.h>
#include <math.h>

#define B_   32
#define T_   64
#define D_   300
#define H_   256
#define G4H  1024   // 4*H
#define M_   64
#define C_   5

typedef _Float16 h2v __attribute__((ext_vector_type(2)));
typedef _Float16 h8  __attribute__((ext_vector_type(8)));
typedef float    f4  __attribute__((ext_vector_type(4)));

__device__ __forceinline__ float sigmoidf_(float x) { return 1.0f / (1.0f + expf(-x)); }

__device__ __forceinline__ float dot2_(h2v a, h2v b, float c) {
#if __has_builtin(__builtin_amdgcn_fdot2)
    return __builtin_amdgcn_fdot2(a, b, c, false);
#else
    return c + (float)a[0] * (float)b[0] + (float)a[1] * (float)b[1];
#endif
}

// LDS-only barrier: waits own LDS ops, does NOT drain global loads (vmcnt)
// — unlike __syncthreads(), which emits s_waitcnt vmcnt(0) lgkmcnt(0).
// sched_barrier(0) pins code motion so nothing is hoisted above s_barrier.
#define BAR_LDS()                                                   \
    do {                                                            \
        asm volatile("s_waitcnt lgkmcnt(0)" ::: "memory");          \
        __builtin_amdgcn_s_barrier();                               \
        __builtin_amdgcn_sched_barrier(0);                          \
    } while (0)

// ---------------------------------------------------------------------------
// K1: length[b]. Coalesced: 16 lanes per t read 64B-contiguous segments.
// ---------------------------------------------------------------------------
__global__ void __launch_bounds__(1024)
k_length(const float* __restrict__ x, int* __restrict__ length) {
    const int b   = blockIdx.x;
    const int tid = threadIdx.x;
    const int t   = tid >> 4;        // 0..63
    const int j   = tid & 15;        // lane within 16-group

    __shared__ int cnt;
    if (tid == 0) cnt = 0;
    __syncthreads();

    const float* row = x + (size_t)(b * T_ + t) * D_;
    float mv = 0.f;
    #pragma unroll
    for (int i = 0; i < 19; ++i) {
        int d = j + 16 * i;
        if (d < D_) mv = fmaxf(mv, fabsf(row[d]));
    }
    #pragma unroll
    for (int off = 8; off >= 1; off >>= 1) mv = fmaxf(mv, __shfl_xor(mv, off));
    if (j == 0 && mv > 0.f) atomicAdd(&cnt, 1);
    __syncthreads();
    if (tid == 0) length[b] = cnt;
}

// ---------------------------------------------------------------------------
// K2: xw = x-part of gate pre-activations (+ bias). f16 MFMA GEMM.
// ---------------------------------------------------------------------------
__global__ void __launch_bounds__(256)
k_xw(const float* __restrict__ x,
     const float* __restrict__ Wfw, const float* __restrict__ bfw,
     const float* __restrict__ Wbw, const float* __restrict__ bbw,
     float* __restrict__ xw) {
    const int nt  = blockIdx.x;       // 0..15 col tile
    const int mt  = blockIdx.y;       // 0..15 row tile
    const int tid = threadIdx.x;      // 256
    const int w   = tid >> 6;         // wave 0..3
    const int l   = tid & 63;
    const int n0  = nt * 128, m0 = mt * 128;
    const int dir = n0 >> 10;               // 1024%128==0: tiles don't straddle
    const float* W    = dir ? Wbw : Wfw;
    const float* bias = dir ? bbw : bfw;
    const int ncol0 = n0 & 1023;

    __shared__ __align__(16) _Float16 As[128][40];  // 32 k + 8 pad
    __shared__ __align__(16) _Float16 Bs[128][40];  // [col][k]

    f4 acc[4][4];
    #pragma unroll
    for (int i = 0; i < 4; ++i)
        #pragma unroll
        for (int j = 0; j < 4; ++j) acc[i][j] = (f4){0.f, 0.f, 0.f, 0.f};

    const int wr = (w >> 1) * 64;   // wave row quadrant
    const int wc = (w & 1) * 64;    // wave col quadrant

    for (int k0 = 0; k0 < 320; k0 += 32) {
        // A: 128 rows x 32 k, float4 along k (D_=300 is 4-aligned)
        #pragma unroll
        for (int p = 0; p < 4; ++p) {
            int row = (tid >> 3) + p * 32;
            int kq  = tid & 7;
            int k   = k0 + kq * 4;
            f4 v = (k < D_) ? *(const f4*)&x[(size_t)(m0 + row) * D_ + k]
                            : (f4){0.f, 0.f, 0.f, 0.f};
            _Float16* dst = &As[row][kq * 4];
            dst[0] = (_Float16)v[0]; dst[1] = (_Float16)v[1];
            dst[2] = (_Float16)v[2]; dst[3] = (_Float16)v[3];
        }
        // B: 32 k x 128 cols, float4 along col
        #pragma unroll
        for (int p = 0; p < 4; ++p) {
            int kk   = (tid >> 5) + p * 8;
            int colq = tid & 31;
            int k    = k0 + kk;
            f4 v = (k < D_) ? *(const f4*)&W[(size_t)k * G4H + ncol0 + colq * 4]
                            : (f4){0.f, 0.f, 0.f, 0.f};
            #pragma unroll
            for (int i = 0; i < 4; ++i) Bs[colq * 4 + i][kk] = (_Float16)v[i];
        }
        __syncthreads();

        h8 afr[4], bfr[4];
        #pragma unroll
        for (int fr = 0; fr < 4; ++fr)
            afr[fr] = *(const h8*)&As[wr + fr * 16 + (l & 15)][(l >> 4) * 8];
        #pragma unroll
        for (int fc = 0; fc < 4; ++fc)
            bfr[fc] = *(const h8*)&Bs[wc + fc * 16 + (l & 15)][(l >> 4) * 8];
        #pragma unroll
        for (int fr = 0; fr < 4; ++fr)
            #pragma unroll
            for (int fc = 0; fc < 4; ++fc)
                acc[fr][fc] = __builtin_amdgcn_mfma_f32_16x16x32_f16(
                    afr[fr], bfr[fc], acc[fr][fc], 0, 0, 0);
        __syncthreads();
    }

    #pragma unroll
    for (int fc = 0; fc < 4; ++fc) {
        int col = ncol0 + wc + fc * 16 + (l & 15);
        float bv = bias[col];
        #pragma unroll
        for (int fr = 0; fr < 4; ++fr) {
            #pragma unroll
            for (int e = 0; e < 4; ++e) {
                int row = m0 + wr + fr * 16 + (l >> 4) * 4 + e;
                xw[(size_t)dir * 2048 * G4H + (size_t)row * G4H + col] =
                    acc[fr][fc][e] + bv;
            }
        }
    }
}

// ---------------------------------------------------------------------------
// K3: LSTM recurrence + FUSED einsum (round-8 structure) with double-
// buffered stream prefetch AND raw LDS-only barriers (BAR_LDS) in the main
// loop: global loads (ent/xw) stay in flight ACROSS barriers instead of
// being drained by __syncthreads' implicit s_waitcnt vmcnt(0) — the 16 KB/
// block/step ent burst now genuinely overlaps the publish->poll L3 RTT.
// Exchange protocol unchanged (tagged data, fp32 LSB parity, 4-slot ring,
// relaxed agent atomics). Protocol never relied on the barrier drain:
// peers spin until the tagged word lands; ring distance-4 overwrite is
// excluded because a peer must OBSERVE step-s before we reach s+4.
// ---------------------------------------------------------------------------
__global__ void __launch_bounds__(512)
k_lstm(const float* __restrict__ Wfw, const float* __restrict__ Wbw,
       const float* __restrict__ xw, const int* __restrict__ length,
       const float* __restrict__ ent, float* __restrict__ partials,
       unsigned* __restrict__ exbuf) {
    const int bid = blockIdx.x;
    const int js  = bid >> 6;        // 0..3 column slice
    const int g   = bid & 63;        // group id
    const int dir = g >> 5;
    const int b   = g & 31;
    const int tid = threadIdx.x;     // 0..511
    const int w   = tid >> 6;        // wave 0..7
    const int l   = tid & 63;
    const int c     = w * 32 + (l & 31);   // gate-col 0..255 (gate = c>>6, jj = c&63)
    const int khalf = l >> 5;              // 0: k 0..127, 1: k 128..255
    const int colg  = (c >> 6) * 256 + js * 64 + (c & 63);
    const int m8  = tid >> 3;        // einsum m 0..63
    const int oct = tid & 7;         // einsum d-octet

    __shared__ __align__(8) _Float16 hl_h[256];
    __shared__ float zfin[256];
    __shared__ float ho_l[64];

    const float* Wg = dir ? Wbw : Wfw;

    // ---- stage this thread's W_h column-half into registers (f16 pairs) ----
    h2v wreg[64];
    #pragma unroll
    for (int p = 0; p < 64; ++p) {
        int k = khalf * 128 + 2 * p;
        float w0 = Wg[(size_t)(D_ + k) * G4H + colg];
        float w1 = Wg[(size_t)(D_ + k + 1) * G4H + colg];
        h2v t; t[0] = (_Float16)w0; t[1] = (_Float16)w1;
        wreg[p] = t;
    }

    if (tid < 256) hl_h[tid] = (_Float16)0.f;
    const int len = length[b];
    const size_t xrow = (size_t)(dir * B_ + b) * T_;
    // einsum base: ent[m8, b, t, dir*256 + js*64 + oct*8]
    const float* entp = ent + (((size_t)m8 * B_ + b) * T_) * 512
                            + dir * 256 + js * 64 + oct * 8;
    f4 accA = (f4){0.f, 0.f, 0.f, 0.f};
    f4 accB = (f4){0.f, 0.f, 0.f, 0.f};

    // ---- prefetch step-0 stream operands ----
    const int tt0 = dir ? (T_ - 1) : 0;
    f4 e0 = *(const f4*)(entp + (size_t)tt0 * 512);
    f4 e1 = *(const f4*)(entp + (size_t)tt0 * 512 + 4);
    float xv = (l < 32) ? xw[(xrow + tt0) * G4H + colg] : 0.f;
    __syncthreads();

    float cst = 0.f, hprev = 0.f;

    for (int s = 0; s < T_; ++s) {
        const int tt = dir ? (T_ - 1 - s) : s;
        const unsigned tag = ((unsigned)(s >> 2) & 1u) ^ 1u;   // ring-cycle parity
        const size_t slotBase = ((size_t)g * 4 + (s & 3)) * 256;

        // ---- issue step s+1's stream loads NOW (stay in flight across BAR_LDS) ----
        const int sn  = (s + 1 < T_) ? s + 1 : s;          // clamp: harmless re-read
        const int ttn = dir ? (T_ - 1 - sn) : sn;
        f4 e0n = *(const f4*)(entp + (size_t)ttn * 512);
        f4 e1n = *(const f4*)(entp + (size_t)ttn * 512 + 4);
        float xvn = (l < 32) ? xw[(xrow + ttn) * G4H + colg] : 0.f;

        // ---- dot: this col, this k-half: 32 broadcast b64 reads + 64 fdot2 ----
        float acc = 0.f;
        const uint2* hp = (const uint2*)&hl_h[khalf * 128];
        #pragma unroll
        for (int j = 0; j < 32; ++j) {
            uint2 hv = hp[j];
            acc = dot2_(wreg[2 * j],     __builtin_bit_cast(h2v, hv.x), acc);
            acc = dot2_(wreg[2 * j + 1], __builtin_bit_cast(h2v, hv.y), acc);
        }
        acc += __shfl_xor(acc, 32);          // combine the two k-halves
        if (l < 32) zfin[c] = acc + xv;
        BAR_LDS();                           // zfin visible; globals NOT drained

        // ---- gates for this block's 64 h-columns; publish tagged h slice ----
        if (tid < 64) {
            float zi = zfin[tid], zj = zfin[64 + tid], zf = zfin[128 + tid], zo = zfin[192 + tid];
            float cn = sigmoidf_(zf + 1.0f) * cst + sigmoidf_(zi) * tanhf(zj);
            float hn = sigmoidf_(zo) * tanhf(cn);
            bool  msk = (tt < len);
            float ho  = msk ? hn : 0.f;
            float hk2 = msk ? hn : hprev;
            if (msk) cst = cn;
            hprev = hk2;
            int jglob = js * 64 + tid;
            ho_l[tid] = ho;                  // masked output for fused einsum
            hl_h[jglob] = (_Float16)hk2;     // own slice straight into LDS
            unsigned bits = (__float_as_uint(hk2) & ~1u) | tag;
            __hip_atomic_store(&exbuf[slotBase + jglob], bits,
                               __ATOMIC_RELAXED, __HIP_MEMORY_SCOPE_AGENT);
        }

        // ---- poll peers' tagged words (single L3 trip, relaxed) ----
        if (tid < 256 && (tid >> 6) != js) {
            unsigned v; unsigned it = 0;
            for (;;) {
                v = __hip_atomic_load(&exbuf[slotBase + tid],
                                      __ATOMIC_RELAXED, __HIP_MEMORY_SCOPE_AGENT);
                if ((v & 1u) == tag) break;
                __builtin_amdgcn_s_sleep(1);
                if (++it > (1u << 20)) break;   // safety valve: wrong > wedged
            }
            hl_h[tid] = (_Float16)__uint_as_float(v);
        }
        BAR_LDS();                           // hl_h/ho_l visible; globals NOT drained

        // ---- fused einsum MAC (consumes step-s operands prefetched last iter) ----
        #pragma unroll
        for (int i = 0; i < 4; ++i) {
            accA[i] += e0[i] * ho_l[oct * 8 + i];
            accB[i] += e1[i] * ho_l[oct * 8 + 4 + i];
        }
        e0 = e0n; e1 = e1n; xv = xvn;        // rotate double buffer
    }

    // ---- write partials: unique region per block: (m8, b, 64-d slice) ----
    float* pp = partials + ((size_t)m8 * B_ + b) * 512 + dir * 256 + js * 64 + oct * 8;
    *(f4*)pp = accA;
    *(f4*)(pp + 4) = accB;
}

// ---------------------------------------------------------------------------
// K5: reduce partials over b -> output_f, then l1 = relu(of @ W1 + b1)
// ---------------------------------------------------------------------------
__global__ void k_l1(const float* __restrict__ partials, const float* __restrict__ W1,
                     const float* __restrict__ b1, float* __restrict__ l1) {
    const int m = blockIdx.x;
    const int j = threadIdx.x;  // 0..255
    __shared__ float of[512];
    for (int d = j; d < 512; d += 256) {
        float s = 0.f;
        #pragma unroll
        for (int cc = 0; cc < 32; ++cc) s += partials[((size_t)m * B_ + cc) * 512 + d];
        of[d] = s * (1.0f / T_);
    }
    __syncthreads();
    float z = b1[j];
    for (int k = 0; k < 512; ++k) z += of[k] * W1[(size_t)k * H_ + j];
    l1[(size_t)m * H_ + j] = fmaxf(z, 0.f);
}

// ---------------------------------------------------------------------------
// K6: head + loss
// ---------------------------------------------------------------------------
__global__ void k_head(const float* __restrict__ l1, const float* __restrict__ W2,
                       const float* __restrict__ b2, const int* __restrict__ labels,
                       float* __restrict__ out) {
    const int tid = threadIdx.x;  // 320 threads
    __shared__ float red[320];
    float term = 0.f;
    if (tid < 320) {
        int m = tid / 5, cc = tid % 5;
        float z = b2[cc];
        for (int k = 0; k < H_; ++k) z += l1[(size_t)m * H_ + k] * W2[(size_t)k * C_ + cc];
        float p = 1.f / (1.f + expf(-z));
        out[tid] = p;
        term = -(float)labels[tid] * logf(p);
    }
    red[tid] = term;
    __syncthreads();
    if (tid == 0) {
        float s = 0.f;
        for (int i = 0; i < 320; ++i) s += red[i];
        out[320] = s / (float)C_;
    }
}

// ---------------------------------------------------------------------------
extern "C" void kernel_launch(void* const* d_in, const int* in_sizes, int n_in,
                              void* d_out, int out_size, void* d_ws, size_t ws_size,
                              hipStream_t stream) {
    const float* x      = (const float*)d_in[0];
    const float* ent    = (const float*)d_in[1];
    const int*   labels = (const int*)d_in[2];
    const float* Wfw    = (const float*)d_in[3];
    const float* bfw    = (const float*)d_in[4];
    const float* Wbw    = (const float*)d_in[5];
    const float* bbw    = (const float*)d_in[6];
    const float* W1     = (const float*)d_in[7];
    const float* b1     = (const float*)d_in[8];
    const float* W2     = (const float*)d_in[9];
    const float* b2     = (const float*)d_in[10];
    float* out = (float*)d_out;

    float*    ws       = (float*)d_ws;
    float*    xw       = ws;                            // 4,194,304 floats
    unsigned* exbuf    = (unsigned*)(xw + 4194304);     // 65,536 u32
    float*    l1       = (float*)(exbuf + 65536);       // 16,384 floats
    int*      length   = (int*)(l1 + 16384);            // 32 ints
    float*    partials = (float*)(length + 32);         // 1,048,576 floats

    k_length<<<32, 1024, 0, stream>>>(x, length);
    k_xw<<<dim3(16, 16), 256, 0, stream>>>(x, Wfw, bfw, Wbw, bbw, xw);
    k_lstm<<<256, 512, 0, stream>>>(Wfw, Wbw, xw, length, ent, partials, exbuf);
    k_l1<<<64, 256, 0, stream>>>(partials, W1, b1, l1);
    k_head<<<1, 320, 0, stream>>>(l1, W2, b2, labels, out);
}